// Round 1
// baseline (42159.601 us; speedup 1.0000x reference)
//
#include <hip/hip_runtime.h>

#define V_SZ 50000
#define E_SZ 256
#define H_SZ 512
#define B_SZ 16
#define S_SZ 400
#define T_SZ 100
#define UNK_TOK 1
#define NEGV -1e30f

typedef unsigned short u16;
typedef unsigned int u32;

__device__ __forceinline__ float bf2f(u16 u){ return __uint_as_float(((u32)u)<<16); }
__device__ __forceinline__ u16 f2bf(float x){
  u32 u = __float_as_uint(x);
  u32 r = (u + 0x7fffu + ((u>>16)&1u)) >> 16;
  return (u16)r;
}
__device__ __forceinline__ float wsum(float v){
  #pragma unroll
  for (int o=32;o;o>>=1) v += __shfl_xor(v,o);
  return v;
}
__device__ __forceinline__ float wmaxf(float v){
  #pragma unroll
  for (int o=32;o;o>>=1) v = fmaxf(v, __shfl_xor(v,o));
  return v;
}
__device__ __forceinline__ float ftanh(float x){
  float y = fminf(18.f, fmaxf(-18.f, 2.f*x));
  float e = __expf(y);
  return (e-1.f)/(e+1.f);
}
__device__ __forceinline__ float sigf(float x){ return 1.f/(1.f+__expf(-x)); }

// ---------------- init: zero recurrent state ----------------
__global__ void k_init(float* h_state, float* cov, float* loss_acc){
  int idx = blockIdx.x*256 + threadIdx.x;
  if (idx < 2*2*B_SZ*H_SZ) h_state[idx] = 0.f;
  if (idx < B_SZ*S_SZ) cov[idx] = 0.f;
  if (idx < B_SZ) loss_acc[idx] = 0.f;
}

// ---------------- transposes ----------------
__global__ void k_transpose(const float* __restrict__ in, float* __restrict__ out, int R, int C){
  __shared__ float t[32][33];
  int c0 = blockIdx.x*32, r0 = blockIdx.y*32;
  int x = threadIdx.x, y = threadIdx.y;
  for (int j=y;j<32;j+=8){
    int r=r0+j, c=c0+x;
    t[j][x] = (r<R && c<C) ? in[r*C+c] : 0.f;
  }
  __syncthreads();
  for (int j=y;j<32;j+=8){
    int oc = c0+j, orr = r0+x;
    if (oc<C && orr<R) out[oc*R+orr] = t[x][j];
  }
}
__global__ void k_transpose_bf(const float* __restrict__ in, u16* __restrict__ out, int R, int C){
  __shared__ float t[32][33];
  int c0 = blockIdx.x*32, r0 = blockIdx.y*32;
  int x = threadIdx.x, y = threadIdx.y;
  for (int j=y;j<32;j+=8){
    int r=r0+j, c=c0+x;
    t[j][x] = (r<R && c<C) ? in[r*C+c] : 0.f;
  }
  __syncthreads();
  for (int j=y;j<32;j+=8){
    int oc = c0+j, orr = r0+x;
    if (oc<C && orr<R) out[oc*R+orr] = f2bf(t[x][j]);
  }
}
// fW (50000 x 1024) -> paired-bf16 k-major: out[k2*V + v] = pack(bf16(fW[v][2k2]), bf16(fW[v][2k2+1]))
__global__ void k_transpose_fw(const float* __restrict__ fW, u32* __restrict__ out){
  __shared__ float t[64][65];
  int v0 = blockIdx.x*64, k0 = blockIdx.y*64;
  int tid = threadIdx.x;
  int r = tid >> 2, cs = (tid & 3)*16;
  int v = v0 + r;
  if (v < V_SZ){
    const float* src = fW + (size_t)v*1024 + k0 + cs;
    #pragma unroll
    for (int i=0;i<16;++i) t[r][cs+i] = src[i];
  } else {
    #pragma unroll
    for (int i=0;i<16;++i) t[r][cs+i] = 0.f;
  }
  __syncthreads();
  int vl = tid & 63; int vv = v0 + vl;
  if (vv < V_SZ){
    #pragma unroll
    for (int i=0;i<8;++i){
      int kl2 = (tid>>6) + i*4;
      float lo = t[vl][kl2*2], hi = t[vl][kl2*2+1];
      out[(size_t)((k0>>1)+kl2)*V_SZ + vv] = (u32)f2bf(lo) | ((u32)f2bf(hi)<<16);
    }
  }
}

// ---------------- gathers ----------------
__global__ void k_gather_src(const int* __restrict__ src, const float* __restrict__ emb, float* __restrict__ xs){
  const int n = S_SZ*B_SZ*E_SZ;
  for (int idx = blockIdx.x*blockDim.x + threadIdx.x; idx < n; idx += gridDim.x*blockDim.x){
    int e = idx & 255; int sb = idx >> 8; int b = sb & 15; int s = sb >> 4;
    int tok = src[b*S_SZ + s]; if (tok >= V_SZ) tok = UNK_TOK;
    xs[idx] = emb[tok*E_SZ + e];
  }
}
__global__ void k_gather_dec(const int* __restrict__ tgt, const float* __restrict__ emb, float* __restrict__ dx){
  const int n = (T_SZ-1)*B_SZ*E_SZ;
  for (int idx = blockIdx.x*blockDim.x + threadIdx.x; idx < n; idx += gridDim.x*blockDim.x){
    int e = idx & 255; int tb = idx >> 8; int b = tb & 15; int t = tb >> 4;
    int tok = tgt[b*T_SZ + t]; if (tok >= V_SZ) tok = UNK_TOK;
    dx[idx] = emb[tok*E_SZ + e];
  }
}
__global__ void k_gxscore(const float* __restrict__ dx, const float* __restrict__ gW, float* __restrict__ gx){
  int i = blockIdx.x*blockDim.x + threadIdx.x;
  if (i < (T_SZ-1)*B_SZ){
    const float* x = dx + i*E_SZ;
    const float* g = gW + 1024;
    float a = 0.f;
    for (int e=0;e<E_SZ;++e) a += x[e]*g[e];
    gx[i] = a;
  }
}

// ---------------- generic GEMM: C(M,N) = A(M,K) @ WT(K,N) + bias(N) ----------------
__global__ __launch_bounds__(256) void k_gemm(const float* __restrict__ A, const float* __restrict__ WT,
                       const float* __restrict__ bias, float* __restrict__ C,
                       int M, int N, int K){
  __shared__ float As[32][36];
  int n = blockIdx.x*64 + (threadIdx.x & 63);
  int wv = threadIdx.x >> 6;
  int m0 = blockIdx.y*32;
  float acc[8];
  #pragma unroll
  for (int j=0;j<8;++j) acc[j]=0.f;
  for (int k0=0;k0<K;k0+=32){
    for (int e=threadIdx.x; e<1024; e+=256){
      int r = e>>5, c = e&31;
      int m = m0 + r;
      As[c][r] = (m<M)? A[m*K + k0 + c] : 0.f;
    }
    __syncthreads();
    #pragma unroll 8
    for (int k=0;k<32;++k){
      float w = WT[(k0+k)*N + n];
      const float* as = &As[k][wv*8];
      #pragma unroll
      for (int j=0;j<8;++j) acc[j] += as[j]*w;
    }
    __syncthreads();
  }
  float bv = bias[n];
  #pragma unroll
  for (int j=0;j<8;++j){
    int m = m0 + wv*8 + j;
    if (m<M) C[m*N + n] = acc[j] + bv;
  }
}

// ---------------- encoder step (fwd+bwd fused) ----------------
__global__ __launch_bounds__(384) void k_enc_step(
    const float* __restrict__ gi_f, const float* __restrict__ gi_b,
    const u16* __restrict__ WTf, const u16* __restrict__ WTb,
    const float* __restrict__ bhhf, const float* __restrict__ bhhb,
    float* __restrict__ h_state, float* __restrict__ enc_out, int t){
  int bid = blockIdx.x;
  int d = bid >> 6; int rem = bid & 63; int b = rem >> 2; int ht = rem & 3; int h0 = ht*128;
  int pos = d ? (S_SZ-1-t) : t;
  const float* gi = (d ? gi_b : gi_f) + (pos*B_SZ + b)*1536;
  const u16* WT = d ? WTb : WTf;
  const float* bhh = d ? bhhb : bhhf;
  int rbuf = t & 1;
  const float* hp = h_state + ((rbuf*2 + d)*B_SZ + b)*H_SZ;
  float* hn = h_state + ((((rbuf^1)*2) + d)*B_SZ + b)*H_SZ;
  __shared__ float hl[512];
  __shared__ float ghl[384];
  int tid = threadIdx.x;
  for (int i=tid;i<512;i+=384) hl[i] = hp[i];
  __syncthreads();
  int g = (tid>>7)*512 + h0 + (tid&127);
  float acc = bhh[g];
  const u16* w = WT + g;
  #pragma unroll 8
  for (int k=0;k<512;++k) acc += hl[k]*bf2f(w[k*1536]);
  ghl[tid] = acc;
  __syncthreads();
  if (tid < 128){
    int h = h0 + tid;
    float r = sigf(gi[h] + ghl[tid]);
    float z = sigf(gi[512+h] + ghl[128+tid]);
    float nn = ftanh(gi[1024+h] + r*ghl[256+tid]);
    float hv = (1.f-z)*nn + z*hl[h];
    hn[h] = hv;
    enc_out[(b*S_SZ + pos)*1024 + d*512 + h] = hv;
  }
}

__global__ void k_pack_hidden(const float* __restrict__ h_state, float* __restrict__ eh){
  int idx = blockIdx.x*256 + threadIdx.x;
  if (idx < B_SZ*1024){
    int b = idx >> 10, k = idx & 1023;
    int d = k >> 9;
    eh[idx] = h_state[((0*2 + d)*B_SZ + b)*H_SZ + (k & 511)];  // final states live in buf 0
  }
}

// ---------------- decoder GRU (carry = prev ctx_red, per reference) ----------------
__global__ __launch_bounds__(384) void k_dec_gru(
    const float* __restrict__ dec_gi, const float* __restrict__ h_cur,
    const u16* __restrict__ WT, const float* __restrict__ bhh,
    float* __restrict__ hdec, float* __restrict__ u_t, int t){
  int bid = blockIdx.x; int b = bid >> 2; int ht = bid & 3; int h0 = ht*128;
  const float* gi = dec_gi + (t*B_SZ + b)*1536;
  const float* hp = h_cur + b*H_SZ;
  __shared__ float hl[512]; __shared__ float ghl[384];
  int tid = threadIdx.x;
  for (int i=tid;i<512;i+=384) hl[i] = hp[i];
  __syncthreads();
  int g = (tid>>7)*512 + h0 + (tid&127);
  float acc = bhh[g];
  const u16* w = WT + g;
  #pragma unroll 8
  for (int k=0;k<512;++k) acc += hl[k]*bf2f(w[k*1536]);
  ghl[tid] = acc;
  __syncthreads();
  if (tid<128){
    int h = h0 + tid;
    float r = sigf(gi[h] + ghl[tid]);
    float z = sigf(gi[512+h] + ghl[128+tid]);
    float nn = ftanh(gi[1024+h] + r*ghl[256+tid]);
    float hv = (1.f-z)*nn + z*hl[h];
    hdec[b*H_SZ + h] = hv;
    u_t[(512+h)*B_SZ + b] = hv;
  }
}

// ---------------- attention scores ----------------
__global__ __launch_bounds__(512) void k_escore(
    const float* __restrict__ WhEnc, const float* __restrict__ s_part,
    const float* __restrict__ cov, const float* __restrict__ aWc,
    const float* __restrict__ abc, const float* __restrict__ aV,
    const float* __restrict__ abv, const float* __restrict__ mask,
    float* __restrict__ e_buf){
  int b = blockIdx.x >> 3; int s0 = (blockIdx.x & 7)*50;
  int tid = threadIdx.x, lane = tid & 63, w = tid >> 6;
  __shared__ float sp[512], wc[512], ab[512], av[512];
  sp[tid] = s_part[b*H_SZ + tid];
  wc[tid] = aWc[tid];
  ab[tid] = abc[tid];
  av[tid] = aV[tid];
  __syncthreads();
  float abv0 = abv[0];
  for (int s = s0 + w; s < s0+50; s += 8){
    float cv = cov[b*S_SZ + s];
    const float* wh = WhEnc + (b*S_SZ + s)*H_SZ;
    float a = 0.f;
    #pragma unroll
    for (int j=0;j<8;++j){
      int h = j*64 + lane;
      a += ftanh(wh[h] + sp[h] + cv*wc[h] + ab[h]) * av[h];
    }
    a = wsum(a);
    if (lane == 0){
      float e = a + abv0;
      if (!(mask[b*S_SZ + s] > 0.f)) e = NEGV;
      e_buf[b*S_SZ + s] = e;
    }
  }
}

// ---------------- softmax + coverage update ----------------
__global__ __launch_bounds__(512) void k_attn_soft(
    const float* __restrict__ e_buf, float* __restrict__ attn,
    float* __restrict__ cov, float* __restrict__ covloss){
  int b = blockIdx.x; int tid = threadIdx.x, lane = tid & 63, w = tid >> 6;
  __shared__ float red[16];
  float e = (tid < S_SZ) ? e_buf[b*S_SZ + tid] : NEGV;
  float m = wmaxf(e);
  if (lane==0) red[w] = m;
  __syncthreads();
  if (tid < 64){
    float x = (lane < 8) ? red[lane] : NEGV;
    x = wmaxf(x);
    if (lane==0) red[8] = x;
  }
  __syncthreads();
  float mx = red[8];
  float pv = (tid < S_SZ) ? __expf(e - mx) : 0.f;
  float sm = wsum(pv);
  if (lane==0) red[w] = sm;
  __syncthreads();
  if (tid < 64){
    float x = (lane<8)? red[lane] : 0.f;
    x = wsum(x);
    if (lane==0) red[9] = x;
  }
  __syncthreads();
  float inv = 1.f/red[9];
  float ml = 0.f;
  if (tid < S_SZ){
    float a = pv*inv;
    attn[b*S_SZ+tid] = a;
    float cn = cov[b*S_SZ+tid] + a;
    cov[b*S_SZ+tid] = cn;
    ml = fminf(a, cn);
  }
  __syncthreads();
  float cs = wsum(ml);
  if (lane==0) red[w] = cs;
  __syncthreads();
  if (tid==0){
    float tot=0.f;
    for (int i=0;i<8;++i) tot += red[i];
    covloss[b] = tot;
  }
}

// ---------------- context vector ----------------
__global__ __launch_bounds__(128) void k_ctx(
    const float* __restrict__ attn, const float* __restrict__ enc_out,
    float* __restrict__ ctx){
  int b = blockIdx.x >> 3; int d0 = (blockIdx.x & 7)*128;
  int tid = threadIdx.x;
  float a = 0.f;
  const float* ao = attn + b*S_SZ;
  const float* eo = enc_out + b*S_SZ*1024 + d0 + tid;
  for (int s=0;s<S_SZ;++s) a += ao[s]*eo[s*1024];
  ctx[b*1024 + d0 + tid] = a;
}

// ---------------- u pack + p_gen ----------------
__global__ __launch_bounds__(512) void k_uprep(
    const float* __restrict__ h_cur, const float* __restrict__ hdec,
    const float* __restrict__ gW, const float* __restrict__ gb,
    const float* __restrict__ gx, float* __restrict__ u_t,
    float* __restrict__ p_gen, int t){
  int tid = threadIdx.x, lane = tid&63, w = tid>>6;
  for (int idx=tid; idx<8192; idx+=512){
    int k = idx >> 4, b = idx & 15;
    u_t[idx] = h_cur[b*H_SZ + k];
  }
  for (int b = w; b < 16; b += 8){
    float a = 0.f;
    #pragma unroll
    for (int j=0;j<8;++j){
      int k = j*64 + lane;
      a += h_cur[b*H_SZ+k]*gW[k] + hdec[b*H_SZ+k]*gW[512+k];
    }
    a = wsum(a);
    if (lane==0){
      float sc = a + gx[t*B_SZ + b] + gb[0];
      float pg = sigf(sc);
      pg = fminf(0.999f, fmaxf(0.001f, pg));
      p_gen[b] = pg;
    }
  }
}

// ---------------- vocab logits: sumexp partials + logit at target ----------------
__global__ __launch_bounds__(256) void k_logits(
    const float* __restrict__ u_t, const u32* __restrict__ fwt2,
    const float* __restrict__ fb, const int* __restrict__ tgt_vecs,
    float* __restrict__ se_part, float* __restrict__ logit_tgt, int t){
  int tid = threadIdx.x;
  int v = blockIdx.x*256 + tid;
  bool valid = v < V_SZ;
  int vv = valid ? v : 0;
  float acc[16];
  #pragma unroll
  for (int b=0;b<16;++b) acc[b]=0.f;
  const u32* fp = fwt2 + vv;
  for (int k2=0;k2<512;++k2){
    u32 pw = fp[(size_t)k2*V_SZ];
    float w0 = __uint_as_float(pw<<16);
    float w1 = __uint_as_float(pw & 0xffff0000u);
    const float* ua = u_t + k2*32;
    #pragma unroll
    for (int b=0;b<16;++b) acc[b] += w0*ua[b] + w1*ua[16+b];
  }
  float fbv = valid ? fb[vv] : 0.f;
  float es[16];
  #pragma unroll
  for (int b=0;b<16;++b){
    float lg = acc[b] + fbv;
    if (valid && v == tgt_vecs[b*T_SZ + t + 1]) logit_tgt[b] = lg;
    es[b] = valid ? __expf(lg) : 0.f;
  }
  #pragma unroll
  for (int b=0;b<16;++b) es[b] = wsum(es[b]);
  __shared__ float wp[4][16];
  int lane = tid&63, w = tid>>6;
  if (lane==0){
    #pragma unroll
    for (int b=0;b<16;++b) wp[w][b] = es[b];
  }
  __syncthreads();
  if (tid<16) se_part[blockIdx.x*16+tid] = wp[0][tid]+wp[1][tid]+wp[2][tid]+wp[3][tid];
}

// ---------------- per-step loss ----------------
__global__ __launch_bounds__(256) void k_final(
    const float* __restrict__ attn, const int* __restrict__ src_vecs,
    const int* __restrict__ tgt_vecs, const float* __restrict__ p_gen,
    const float* __restrict__ logit_tgt, const float* __restrict__ se_part,
    const float* __restrict__ covloss, float* __restrict__ loss_acc, int t){
  int tid = threadIdx.x, lane = tid&63, w = tid>>6;
  __shared__ float sume[16];
  for (int b = w; b < 16; b += 4){
    float a = 0.f;
    for (int i = lane; i < 196; i += 64) a += se_part[i*16 + b];
    a = wsum(a);
    if (lane==0) sume[b] = a;
  }
  __syncthreads();
  for (int b = w; b < 16; b += 4){
    int tgt = tgt_vecs[b*T_SZ + t + 1];
    float sc = 0.f;
    for (int s = lane; s < S_SZ; s += 64){
      if (src_vecs[b*S_SZ + s] == tgt) sc += attn[b*S_SZ + s];
    }
    sc = wsum(sc);
    if (lane==0){
      float pg = p_gen[b];
      float pvv = __expf(logit_tgt[b]) / sume[b];
      float tp = pg*pvv + (1.f-pg)*sc;
      float ls = -logf(tp + 1e-9f) + covloss[b];   // LAMB = 1
      if (tgt != 0) loss_acc[b] += ls;
    }
  }
}

// ---------------- output ----------------
__global__ void k_out(const float* __restrict__ loss_acc, const int* __restrict__ tgt_vecs, float* __restrict__ out){
  __shared__ float s[16];
  int tid = threadIdx.x;
  if (tid < 16){
    int c = 0;
    for (int t=0;t<T_SZ;++t) c += (tgt_vecs[tid*T_SZ + t] != 0) ? 1 : 0;
    s[tid] = loss_acc[tid] / (float)(c - 1);
  }
  __syncthreads();
  if (tid == 0){
    float a = 0.f;
    for (int b=0;b<16;++b) a += s[b];
    out[0] = a / 16.f;
  }
}

extern "C" void kernel_launch(void* const* d_in, const int* in_sizes, int n_in,
                              void* d_out, int out_size, void* d_ws, size_t ws_size,
                              hipStream_t stream){
  (void)in_sizes; (void)n_in; (void)out_size; (void)ws_size;
  const int*   src_vecs = (const int*)d_in[0];
  const float* src_mask = (const float*)d_in[1];
  const int*   tgt_vecs = (const int*)d_in[2];
  const float* enc_embed= (const float*)d_in[4];
  const float* dec_embed= (const float*)d_in[5];
  const float* eWih_f = (const float*)d_in[6];
  const float* eWhh_f = (const float*)d_in[7];
  const float* ebih_f = (const float*)d_in[8];
  const float* ebhh_f = (const float*)d_in[9];
  const float* eWih_b = (const float*)d_in[10];
  const float* eWhh_b = (const float*)d_in[11];
  const float* ebih_b = (const float*)d_in[12];
  const float* ebhh_b = (const float*)d_in[13];
  const float* dWih = (const float*)d_in[14];
  const float* dWhh = (const float*)d_in[15];
  const float* dbih = (const float*)d_in[16];
  const float* dbhh = (const float*)d_in[17];
  const float* aWh  = (const float*)d_in[18];
  const float* abh  = (const float*)d_in[19];
  const float* aWs  = (const float*)d_in[20];
  const float* abs_ = (const float*)d_in[21];
  const float* aWc  = (const float*)d_in[22];
  const float* abc  = (const float*)d_in[23];
  const float* aV   = (const float*)d_in[24];
  const float* abv  = (const float*)d_in[25];
  const float* rW   = (const float*)d_in[26];
  const float* rb   = (const float*)d_in[27];
  const float* gW   = (const float*)d_in[28];
  const float* gb   = (const float*)d_in[29];
  const float* fW   = (const float*)d_in[30];
  const float* fb   = (const float*)d_in[31];
  float* out = (float*)d_out;

  char* p = (char*)d_ws;
  auto alloc = [&](size_t n)->char*{ char* r = p; p += (n + 255) & ~(size_t)255; return r; };
  float* xs      = (float*)alloc((size_t)S_SZ*B_SZ*E_SZ*4);
  float* gi_f    = (float*)alloc((size_t)S_SZ*B_SZ*1536*4);
  float* gi_b    = (float*)alloc((size_t)S_SZ*B_SZ*1536*4);
  float* enc_out = (float*)alloc((size_t)B_SZ*S_SZ*1024*4);
  float* WhEnc   = (float*)alloc((size_t)B_SZ*S_SZ*512*4);
  float* dec_x   = (float*)alloc((size_t)(T_SZ-1)*B_SZ*E_SZ*4);
  float* dec_gi  = (float*)alloc((size_t)(T_SZ-1)*B_SZ*1536*4);
  float* gx      = (float*)alloc((size_t)(T_SZ-1)*B_SZ*4);
  float* eWihT_f = (float*)alloc((size_t)256*1536*4);
  float* eWihT_b = (float*)alloc((size_t)256*1536*4);
  float* dWihT   = (float*)alloc((size_t)256*1536*4);
  float* aWhT    = (float*)alloc((size_t)1024*512*4);
  float* aWsT    = (float*)alloc((size_t)512*512*4);
  float* rWT     = (float*)alloc((size_t)1024*512*4);
  u16* WhhT_f    = (u16*)alloc((size_t)512*1536*2);
  u16* WhhT_b    = (u16*)alloc((size_t)512*1536*2);
  u16* dWhhT     = (u16*)alloc((size_t)512*1536*2);
  u32* fwt2      = (u32*)alloc((size_t)512*V_SZ*4);
  float* h_state = (float*)alloc((size_t)2*2*B_SZ*H_SZ*4);
  float* enc_hid = (float*)alloc((size_t)B_SZ*1024*4);
  float* h_cur   = (float*)alloc((size_t)B_SZ*H_SZ*4);
  float* hdec    = (float*)alloc((size_t)B_SZ*H_SZ*4);
  float* s_part  = (float*)alloc((size_t)B_SZ*H_SZ*4);
  float* e_buf   = (float*)alloc((size_t)B_SZ*S_SZ*4);
  float* attn    = (float*)alloc((size_t)B_SZ*S_SZ*4);
  float* cov     = (float*)alloc((size_t)B_SZ*S_SZ*4);
  float* ctx     = (float*)alloc((size_t)B_SZ*1024*4);
  float* u_t     = (float*)alloc((size_t)1024*B_SZ*4);
  float* se_part = (float*)alloc((size_t)196*16*4);
  float* logit_tgt = (float*)alloc(64*4);
  float* p_gen   = (float*)alloc(64*4);
  float* covloss = (float*)alloc(64*4);
  float* loss_acc= (float*)alloc(64*4);

  dim3 tb(32,8);
  k_init<<<128,256,0,stream>>>(h_state, cov, loss_acc);
  k_transpose<<<dim3(8,48),tb,0,stream>>>(eWih_f, eWihT_f, 1536, 256);
  k_transpose<<<dim3(8,48),tb,0,stream>>>(eWih_b, eWihT_b, 1536, 256);
  k_transpose<<<dim3(8,48),tb,0,stream>>>(dWih, dWihT, 1536, 256);
  k_transpose<<<dim3(32,16),tb,0,stream>>>(aWh, aWhT, 512, 1024);
  k_transpose<<<dim3(16,16),tb,0,stream>>>(aWs, aWsT, 512, 512);
  k_transpose<<<dim3(32,16),tb,0,stream>>>(rW, rWT, 512, 1024);
  k_transpose_bf<<<dim3(16,48),tb,0,stream>>>(eWhh_f, WhhT_f, 1536, 512);
  k_transpose_bf<<<dim3(16,48),tb,0,stream>>>(eWhh_b, WhhT_b, 1536, 512);
  k_transpose_bf<<<dim3(16,48),tb,0,stream>>>(dWhh, dWhhT, 1536, 512);
  k_transpose_fw<<<dim3(782,16),256,0,stream>>>(fW, fwt2);
  k_gather_src<<<1024,256,0,stream>>>(src_vecs, enc_embed, xs);
  k_gather_dec<<<512,256,0,stream>>>(tgt_vecs, dec_embed, dec_x);
  k_gxscore<<<7,256,0,stream>>>(dec_x, gW, gx);
  k_gemm<<<dim3(24,200),256,0,stream>>>(xs, eWihT_f, ebih_f, gi_f, 6400,1536,256);
  k_gemm<<<dim3(24,200),256,0,stream>>>(xs, eWihT_b, ebih_b, gi_b, 6400,1536,256);
  k_gemm<<<dim3(24,50),256,0,stream>>>(dec_x, dWihT, dbih, dec_gi, 1584,1536,256);

  for (int t=0;t<S_SZ;++t)
    k_enc_step<<<128,384,0,stream>>>(gi_f, gi_b, WhhT_f, WhhT_b, ebhh_f, ebhh_b, h_state, enc_out, t);

  k_pack_hidden<<<64,256,0,stream>>>(h_state, enc_hid);
  k_gemm<<<dim3(8,1),256,0,stream>>>(enc_hid, rWT, rb, h_cur, 16,512,1024);
  k_gemm<<<dim3(8,200),256,0,stream>>>(enc_out, aWhT, abh, WhEnc, 6400,512,1024);

  for (int t=0;t<T_SZ-1;++t){
    k_dec_gru<<<64,384,0,stream>>>(dec_gi, h_cur, dWhhT, dbhh, hdec, u_t, t);
    k_gemm<<<dim3(8,1),256,0,stream>>>(hdec, aWsT, abs_, s_part, 16,512,512);
    k_escore<<<128,512,0,stream>>>(WhEnc, s_part, cov, aWc, abc, aV, abv, src_mask, e_buf);
    k_attn_soft<<<16,512,0,stream>>>(e_buf, attn, cov, covloss);
    k_ctx<<<128,128,0,stream>>>(attn, enc_out, ctx);
    k_gemm<<<dim3(8,1),256,0,stream>>>(ctx, rWT, rb, h_cur, 16,512,1024);
    k_uprep<<<1,512,0,stream>>>(h_cur, hdec, gW, gb, gx, u_t, p_gen, t);
    k_logits<<<196,256,0,stream>>>(u_t, fwt2, fb, tgt_vecs, se_part, logit_tgt, t);
    k_final<<<1,256,0,stream>>>(attn, src_vecs, tgt_vecs, p_gen, logit_tgt, se_part, covloss, loss_acc, t);
  }
  k_out<<<1,64,0,stream>>>(loss_acc, tgt_vecs, out);
}

// Round 2
// 25321.996 us; speedup vs baseline: 1.6649x; 1.6649x over previous
//
#include <hip/hip_runtime.h>

#define V_SZ 50000
#define E_SZ 256
#define H_SZ 512
#define B_SZ 16
#define S_SZ 400
#define T_SZ 100
#define UNK_TOK 1
#define NEGV -1e30f

typedef unsigned short u16;
typedef unsigned int u32;
typedef __attribute__((ext_vector_type(8))) short sv8;
typedef __attribute__((ext_vector_type(4))) float f32x4;

__device__ __forceinline__ float bf2f(u16 u){ return __uint_as_float(((u32)u)<<16); }
__device__ __forceinline__ u16 f2bf(float x){
  u32 u = __float_as_uint(x);
  u32 r = (u + 0x7fffu + ((u>>16)&1u)) >> 16;
  return (u16)r;
}
__device__ __forceinline__ float wsum(float v){
  #pragma unroll
  for (int o=32;o;o>>=1) v += __shfl_xor(v,o);
  return v;
}
__device__ __forceinline__ float wmaxf(float v){
  #pragma unroll
  for (int o=32;o;o>>=1) v = fmaxf(v, __shfl_xor(v,o));
  return v;
}
__device__ __forceinline__ float ftanh(float x){
  float y = fminf(18.f, fmaxf(-18.f, 2.f*x));
  float e = __expf(y);
  return (e-1.f)/(e+1.f);
}
__device__ __forceinline__ float sigf(float x){ return 1.f/(1.f+__expf(-x)); }

// ---------------- init ----------------
__global__ void k_init(u32* h_bf, int* bar, float* cov, float* loss_acc){
  int idx = blockIdx.x*256 + threadIdx.x;
  if (idx < 16384) h_bf[idx] = 0u;          // 2 bufs x 2 dirs x 16 b x 512 h bf16
  if (idx < 64) bar[idx] = 0;
  if (idx < B_SZ*S_SZ) cov[idx] = 0.f;
  if (idx < B_SZ) loss_acc[idx] = 0.f;
}

// ---------------- transposes / converts ----------------
__global__ void k_transpose(const float* __restrict__ in, float* __restrict__ out, int R, int C){
  __shared__ float t[32][33];
  int c0 = blockIdx.x*32, r0 = blockIdx.y*32;
  int x = threadIdx.x, y = threadIdx.y;
  for (int j=y;j<32;j+=8){
    int r=r0+j, c=c0+x;
    t[j][x] = (r<R && c<C) ? in[r*C+c] : 0.f;
  }
  __syncthreads();
  for (int j=y;j<32;j+=8){
    int oc = c0+j, orr = r0+x;
    if (oc<C && orr<R) out[oc*R+orr] = t[x][j];
  }
}
__global__ void k_transpose_bf(const float* __restrict__ in, u16* __restrict__ out, int R, int C){
  __shared__ float t[32][33];
  int c0 = blockIdx.x*32, r0 = blockIdx.y*32;
  int x = threadIdx.x, y = threadIdx.y;
  for (int j=y;j<32;j+=8){
    int r=r0+j, c=c0+x;
    t[j][x] = (r<R && c<C) ? in[r*C+c] : 0.f;
  }
  __syncthreads();
  for (int j=y;j<32;j+=8){
    int oc = c0+j, orr = r0+x;
    if (oc<C && orr<R) out[oc*R+orr] = f2bf(t[x][j]);
  }
}
__global__ void k_f2bf(const float* __restrict__ in, u16* __restrict__ out, int n){
  for (int i = blockIdx.x*256 + threadIdx.x; i < n; i += gridDim.x*256) out[i] = f2bf(in[i]);
}
// fW (V,1024) -> fragment-major bf16: out[tile*16384 + kk*512 + lane*8 + j]
//   = fW[tile*16 + (lane&15)][kk*32 + (lane>>4)*8 + j]
__global__ void k_prep_fwB(const float* __restrict__ fW, u16* __restrict__ out){
  int idx = blockIdx.x*256 + threadIdx.x;            // (tile,kk,lane)
  if (idx >= 3125*32*64) return;
  int lane = idx & 63; int kk = (idx>>6) & 31; int tile = idx >> 11;
  int v = tile*16 + (lane&15);
  int k = kk*32 + ((lane>>4)<<3);
  const float* src = fW + (size_t)v*1024 + k;
  u16* dst = out + (size_t)idx*8;
  #pragma unroll
  for (int j=0;j<8;++j) dst[j] = f2bf(src[j]);
}

// ---------------- gathers ----------------
__global__ void k_gather_src(const int* __restrict__ src, const float* __restrict__ emb, float* __restrict__ xs){
  const int n = S_SZ*B_SZ*E_SZ;
  for (int idx = blockIdx.x*blockDim.x + threadIdx.x; idx < n; idx += gridDim.x*blockDim.x){
    int e = idx & 255; int sb = idx >> 8; int b = sb & 15; int s = sb >> 4;
    int tok = src[b*S_SZ + s]; if (tok >= V_SZ) tok = UNK_TOK;
    xs[idx] = emb[tok*E_SZ + e];
  }
}
__global__ void k_gather_dec(const int* __restrict__ tgt, const float* __restrict__ emb, float* __restrict__ dx){
  const int n = (T_SZ-1)*B_SZ*E_SZ;
  for (int idx = blockIdx.x*blockDim.x + threadIdx.x; idx < n; idx += gridDim.x*blockDim.x){
    int e = idx & 255; int tb = idx >> 8; int b = tb & 15; int t = tb >> 4;
    int tok = tgt[b*T_SZ + t]; if (tok >= V_SZ) tok = UNK_TOK;
    dx[idx] = emb[tok*E_SZ + e];
  }
}
__global__ void k_gxscore(const float* __restrict__ dx, const float* __restrict__ gW, float* __restrict__ gx){
  int i = blockIdx.x*blockDim.x + threadIdx.x;
  if (i < (T_SZ-1)*B_SZ){
    const float* x = dx + i*E_SZ;
    const float* g = gW + 1024;
    float a = 0.f;
    for (int e=0;e<E_SZ;++e) a += x[e]*g[e];
    gx[i] = a;
  }
}

// ---------------- generic GEMM: C(M,N) = A(M,K) @ WT(K,N) + bias(N) ----------------
__global__ __launch_bounds__(256) void k_gemm(const float* __restrict__ A, const float* __restrict__ WT,
                       const float* __restrict__ bias, float* __restrict__ C,
                       int M, int N, int K){
  __shared__ float As[32][36];
  int n = blockIdx.x*64 + (threadIdx.x & 63);
  int wv = threadIdx.x >> 6;
  int m0 = blockIdx.y*32;
  float acc[8];
  #pragma unroll
  for (int j=0;j<8;++j) acc[j]=0.f;
  for (int k0=0;k0<K;k0+=32){
    for (int e=threadIdx.x; e<1024; e+=256){
      int r = e>>5, c = e&31;
      int m = m0 + r;
      As[c][r] = (m<M)? A[m*K + k0 + c] : 0.f;
    }
    __syncthreads();
    #pragma unroll 8
    for (int k=0;k<32;++k){
      float w = WT[(k0+k)*N + n];
      const float* as = &As[k][wv*8];
      #pragma unroll
      for (int j=0;j<8;++j) acc[j] += as[j]*w;
    }
    __syncthreads();
  }
  float bv = bias[n];
  #pragma unroll
  for (int j=0;j<8;++j){
    int m = m0 + wv*8 + j;
    if (m<M) C[m*N + n] = acc[j] + bv;
  }
}

// ---------------- grid barrier (device-scope, per-direction) ----------------
__device__ __forceinline__ void grid_barrier(int* bar, int nblk){
  __threadfence();
  __syncthreads();
  if (threadIdx.x == 0){
    int gen = __hip_atomic_load(&bar[1], __ATOMIC_RELAXED, __HIP_MEMORY_SCOPE_AGENT);
    if (__hip_atomic_fetch_add(&bar[0], 1, __ATOMIC_ACQ_REL, __HIP_MEMORY_SCOPE_AGENT) == nblk-1){
      __hip_atomic_store(&bar[0], 0, __ATOMIC_RELAXED, __HIP_MEMORY_SCOPE_AGENT);
      __hip_atomic_fetch_add(&bar[1], 1, __ATOMIC_ACQ_REL, __HIP_MEMORY_SCOPE_AGENT);
    } else {
      while (__hip_atomic_load(&bar[1], __ATOMIC_ACQUIRE, __HIP_MEMORY_SCOPE_AGENT) == gen)
        __builtin_amdgcn_s_sleep(2);
    }
  }
  __syncthreads();
  __threadfence();
}

// ---------------- persistent bidirectional GRU encoder ----------------
// 64 blocks x 64 threads (1 wave). block = dir*32 + slice (slice = 16 h-values).
// Wave owns gates r/z/n for its 16 h x all 16 batches; h_old stays in registers.
// Whh slice (3 x 16 x 512 bf16 = 48KB) staged in LDS as MFMA B-fragments.
__global__ __launch_bounds__(64) void k_enc_persist(
    const float* __restrict__ gi_f, const float* __restrict__ gi_b,
    const u16* __restrict__ Wbf_f, const u16* __restrict__ Wbf_b,
    const float* __restrict__ bhh_f, const float* __restrict__ bhh_b,
    float* __restrict__ enc_out, float* __restrict__ enc_hid,
    u16* __restrict__ h_bf, int* __restrict__ bar){
  __shared__ u16 wl[48*512];   // 48KB
  int lane = threadIdx.x;
  int d = blockIdx.x >> 5, slice = blockIdx.x & 31;
  int h0 = slice*16;
  const u16* Wb = d ? Wbf_b : Wbf_f;
  const float* gi = d ? gi_b : gi_f;
  const float* bhh = d ? bhh_b : bhh_f;
  int* mybar = bar + d*32;
  int hl = h0 + (lane & 15);
  int quad = lane >> 4;

  // stage weight fragments: B[k][n] = Whh[gate*512 + h0 + n][k]
  #pragma unroll 4
  for (int i=0;i<48;++i){
    int gg = i>>4, kk = i&15;
    const u16* src = Wb + ((size_t)(gg*512 + hl))*512 + kk*32 + quad*8;
    *(sv8*)&wl[i*512 + lane*8] = *(const sv8*)src;
  }
  __syncthreads();

  float b0 = bhh[hl], b1 = bhh[512+hl], b2 = bhh[1024+hl];
  float hold[4] = {0.f,0.f,0.f,0.f};

  #pragma unroll 1
  for (int t=0;t<S_SZ;++t){
    int pos = d ? (S_SZ-1-t) : t;
    // gate-input loads (consumed after MFMA; issue early)
    const float* gp = gi + ((size_t)pos*16)*1536 + hl;
    float giv[12];
    #pragma unroll
    for (int gg=0;gg<3;++gg)
      #pragma unroll
      for (int r=0;r<4;++r)
        giv[gg*4+r] = gp[(quad*4 + r)*1536 + gg*512];

    const u16* hb = h_bf + ((size_t)(t&1)*2 + d)*8192 + (lane&15)*512 + quad*8;
    f32x4 a0={0.f,0.f,0.f,0.f}, a1={0.f,0.f,0.f,0.f}, a2={0.f,0.f,0.f,0.f};
    #pragma unroll
    for (int kk=0;kk<16;++kk){
      sv8 a = *(const sv8*)(hb + kk*32);
      a0 = __builtin_amdgcn_mfma_f32_16x16x32_bf16(a, *(const sv8*)&wl[(kk)*512 + lane*8], a0, 0,0,0);
      a1 = __builtin_amdgcn_mfma_f32_16x16x32_bf16(a, *(const sv8*)&wl[(16+kk)*512 + lane*8], a1, 0,0,0);
      a2 = __builtin_amdgcn_mfma_f32_16x16x32_bf16(a, *(const sv8*)&wl[(32+kk)*512 + lane*8], a2, 0,0,0);
    }
    u16* hw = h_bf + ((size_t)((t+1)&1)*2 + d)*8192;
    #pragma unroll
    for (int r=0;r<4;++r){
      int b = quad*4 + r;
      float rg = sigf(giv[r]   + a0[r] + b0);
      float zg = sigf(giv[4+r] + a1[r] + b1);
      float ng = ftanh(giv[8+r] + rg*(a2[r] + b2));
      float hv = (1.f-zg)*ng + zg*hold[r];
      hold[r] = hv;
      enc_out[((size_t)b*S_SZ + pos)*1024 + d*512 + hl] = hv;
      hw[b*512 + hl] = f2bf(hv);
      if (t == S_SZ-1) enc_hid[b*1024 + d*512 + hl] = hv;
    }
    grid_barrier(mybar, 32);
  }
}

// ---------------- decoder GRU (carry = prev ctx_red, per reference) ----------------
__global__ __launch_bounds__(384) void k_dec_gru(
    const float* __restrict__ dec_gi, const float* __restrict__ h_cur,
    const u16* __restrict__ WT, const float* __restrict__ bhh,
    float* __restrict__ hdec, u16* __restrict__ u_bf, int t){
  int bid = blockIdx.x; int b = bid >> 2; int ht = bid & 3; int h0 = ht*128;
  const float* gi = dec_gi + (t*B_SZ + b)*1536;
  const float* hp = h_cur + b*H_SZ;
  __shared__ float hl[512]; __shared__ float ghl[384];
  int tid = threadIdx.x;
  for (int i=tid;i<512;i+=384) hl[i] = hp[i];
  __syncthreads();
  int g = (tid>>7)*512 + h0 + (tid&127);
  float acc = bhh[g];
  const u16* w = WT + g;
  #pragma unroll 8
  for (int k=0;k<512;++k) acc += hl[k]*bf2f(w[k*1536]);
  ghl[tid] = acc;
  __syncthreads();
  if (tid<128){
    int h = h0 + tid;
    float r = sigf(gi[h] + ghl[tid]);
    float z = sigf(gi[512+h] + ghl[128+tid]);
    float nn = ftanh(gi[1024+h] + r*ghl[256+tid]);
    float hv = (1.f-z)*nn + z*hl[h];
    hdec[b*H_SZ + h] = hv;
    u_bf[b*1024 + 512 + h] = f2bf(hv);
  }
}

// ---------------- attention scores ----------------
__global__ __launch_bounds__(512) void k_escore(
    const float* __restrict__ WhEnc, const float* __restrict__ s_part,
    const float* __restrict__ cov, const float* __restrict__ aWc,
    const float* __restrict__ abc, const float* __restrict__ aV,
    const float* __restrict__ abv, const float* __restrict__ mask,
    float* __restrict__ e_buf){
  int b = blockIdx.x >> 3; int s0 = (blockIdx.x & 7)*50;
  int tid = threadIdx.x, lane = tid & 63, w = tid >> 6;
  __shared__ float sp[512], wc[512], ab[512], av[512];
  sp[tid] = s_part[b*H_SZ + tid];
  wc[tid] = aWc[tid];
  ab[tid] = abc[tid];
  av[tid] = aV[tid];
  __syncthreads();
  float abv0 = abv[0];
  for (int s = s0 + w; s < s0+50; s += 8){
    float cv = cov[b*S_SZ + s];
    const float* wh = WhEnc + (b*S_SZ + s)*H_SZ;
    float a = 0.f;
    #pragma unroll
    for (int j=0;j<8;++j){
      int h = j*64 + lane;
      a += ftanh(wh[h] + sp[h] + cv*wc[h] + ab[h]) * av[h];
    }
    a = wsum(a);
    if (lane == 0){
      float e = a + abv0;
      if (!(mask[b*S_SZ + s] > 0.f)) e = NEGV;
      e_buf[b*S_SZ + s] = e;
    }
  }
}

// ---------------- softmax + coverage update ----------------
__global__ __launch_bounds__(512) void k_attn_soft(
    const float* __restrict__ e_buf, float* __restrict__ attn,
    float* __restrict__ cov, float* __restrict__ covloss){
  int b = blockIdx.x; int tid = threadIdx.x, lane = tid & 63, w = tid >> 6;
  __shared__ float red[16];
  float e = (tid < S_SZ) ? e_buf[b*S_SZ + tid] : NEGV;
  float m = wmaxf(e);
  if (lane==0) red[w] = m;
  __syncthreads();
  if (tid < 64){
    float x = (lane < 8) ? red[lane] : NEGV;
    x = wmaxf(x);
    if (lane==0) red[8] = x;
  }
  __syncthreads();
  float mx = red[8];
  float pv = (tid < S_SZ) ? __expf(e - mx) : 0.f;
  float sm = wsum(pv);
  if (lane==0) red[w] = sm;
  __syncthreads();
  if (tid < 64){
    float x = (lane<8)? red[lane] : 0.f;
    x = wsum(x);
    if (lane==0) red[9] = x;
  }
  __syncthreads();
  float inv = 1.f/red[9];
  float ml = 0.f;
  if (tid < S_SZ){
    float a = pv*inv;
    attn[b*S_SZ+tid] = a;
    float cn = cov[b*S_SZ+tid] + a;
    cov[b*S_SZ+tid] = cn;
    ml = fminf(a, cn);
  }
  __syncthreads();
  float cs = wsum(ml);
  if (lane==0) red[w] = cs;
  __syncthreads();
  if (tid==0){
    float tot=0.f;
    for (int i=0;i<8;++i) tot += red[i];
    covloss[b] = tot;
  }
}

// ---------------- context vector ----------------
__global__ __launch_bounds__(128) void k_ctx(
    const float* __restrict__ attn, const float* __restrict__ enc_out,
    float* __restrict__ ctx){
  int b = blockIdx.x >> 3; int d0 = (blockIdx.x & 7)*128;
  int tid = threadIdx.x;
  float a = 0.f;
  const float* ao = attn + b*S_SZ;
  const float* eo = enc_out + b*S_SZ*1024 + d0 + tid;
  for (int s=0;s<S_SZ;++s) a += ao[s]*eo[s*1024];
  ctx[b*1024 + d0 + tid] = a;
}

// ---------------- ctx_red = ctx @ rW.T + rb ; writes h_cur (f32) + u_bf lower half ----------------
__global__ __launch_bounds__(256) void k_ctxred(const float* __restrict__ ctx, const float* __restrict__ rWT,
    const float* __restrict__ rb, float* __restrict__ h_cur, u16* __restrict__ u_bf){
  __shared__ float As[64][17];
  int lane = threadIdx.x & 63, wv = threadIdx.x >> 6;
  int n = blockIdx.x*64 + lane;
  float acc[4] = {0.f,0.f,0.f,0.f};
  for (int k0=0;k0<1024;k0+=64){
    for (int e=threadIdx.x; e<1024; e+=256){
      int r = e & 15, c = e >> 4;
      As[c][r] = ctx[r*1024 + k0 + c];
    }
    __syncthreads();
    #pragma unroll 8
    for (int k=0;k<64;++k){
      float w = rWT[(k0+k)*512 + n];
      #pragma unroll
      for (int j=0;j<4;++j) acc[j] += As[k][wv*4+j]*w;
    }
    __syncthreads();
  }
  float bv = rb[n];
  #pragma unroll
  for (int j=0;j<4;++j){
    int m = wv*4+j;
    float val = acc[j] + bv;
    h_cur[m*512 + n] = val;
    u_bf[m*1024 + n] = f2bf(val);
  }
}

// ---------------- vocab logits via MFMA ----------------
__global__ __launch_bounds__(256) void k_logits_mfma(
    const u16* __restrict__ u_bf, const u16* __restrict__ fwB,
    const float* __restrict__ fb, const int* __restrict__ tgt,
    float* __restrict__ se_part, float* __restrict__ logit_tgt, int t){
  int tid = threadIdx.x, lane = tid & 63, wv = tid >> 6;
  int tile = blockIdx.x*4 + wv;
  bool valid = tile < 3125;
  f32x4 acc = {0.f,0.f,0.f,0.f};
  if (valid){
    const u16* bp = fwB + (size_t)tile*16384 + lane*8;
    const u16* ap = u_bf + (lane&15)*1024 + (lane>>4)*8;
    #pragma unroll 8
    for (int kk=0;kk<32;++kk){
      sv8 a = *(const sv8*)(ap + kk*32);
      sv8 bfr = *(const sv8*)(bp + kk*512);
      acc = __builtin_amdgcn_mfma_f32_16x16x32_bf16(a, bfr, acc, 0,0,0);
    }
  }
  int v = tile*16 + (lane&15);
  float fbv = valid ? fb[v] : 0.f;
  float es0[4];
  #pragma unroll
  for (int r=0;r<4;++r){
    int b = (lane>>4)*4 + r;
    float lg = acc[r] + fbv;
    if (valid && v == tgt[b*T_SZ + t + 1]) logit_tgt[b] = lg;
    es0[r] = valid ? __expf(lg) : 0.f;
  }
  #pragma unroll
  for (int o=1;o<16;o<<=1){
    #pragma unroll
    for (int r=0;r<4;++r) es0[r] += __shfl_xor(es0[r], o);
  }
  __shared__ float part[4][16];
  if ((lane&15)==0){
    #pragma unroll
    for (int r=0;r<4;++r) part[wv][(lane>>4)*4+r] = es0[r];
  }
  __syncthreads();
  if (tid<16) se_part[blockIdx.x*16+tid] = part[0][tid]+part[1][tid]+part[2][tid]+part[3][tid];
}

// ---------------- per-step loss (+ p_gen folded in) ----------------
__global__ __launch_bounds__(256) void k_final(
    const float* __restrict__ attn, const int* __restrict__ src_vecs,
    const int* __restrict__ tgt_vecs, const float* __restrict__ h_cur,
    const float* __restrict__ hdec, const float* __restrict__ gW,
    const float* __restrict__ gb, const float* __restrict__ gx,
    const float* __restrict__ logit_tgt, const float* __restrict__ se_part,
    const float* __restrict__ covloss, float* __restrict__ loss_acc, int t){
  int tid = threadIdx.x, lane = tid&63, w = tid>>6;
  __shared__ float sume[16], pgen[16];
  for (int b = w; b < 16; b += 4){
    float a = 0.f;
    for (int i = lane; i < 782; i += 64) a += se_part[i*16 + b];
    a = wsum(a);
    float dd = 0.f;
    #pragma unroll
    for (int j=0;j<8;++j){
      int k = j*64 + lane;
      dd += h_cur[b*512+k]*gW[k] + hdec[b*512+k]*gW[512+k];
    }
    dd = wsum(dd);
    if (lane==0){
      sume[b] = a;
      float sc = dd + gx[t*B_SZ + b] + gb[0];
      float pg = sigf(sc);
      pgen[b] = fminf(0.999f, fmaxf(0.001f, pg));
    }
  }
  __syncthreads();
  for (int b = w; b < 16; b += 4){
    int tgt = tgt_vecs[b*T_SZ + t + 1];
    float sc = 0.f;
    for (int s = lane; s < S_SZ; s += 64){
      if (src_vecs[b*S_SZ + s] == tgt) sc += attn[b*S_SZ + s];
    }
    sc = wsum(sc);
    if (lane==0){
      float pg = pgen[b];
      float pvv = __expf(logit_tgt[b]) / sume[b];
      float tp = pg*pvv + (1.f-pg)*sc;
      float ls = -logf(tp + 1e-9f) + covloss[b];   // LAMB = 1
      if (tgt != 0) loss_acc[b] += ls;
    }
  }
}

// ---------------- output ----------------
__global__ void k_out(const float* __restrict__ loss_acc, const int* __restrict__ tgt_vecs, float* __restrict__ out){
  __shared__ float s[16];
  int tid = threadIdx.x;
  if (tid < 16){
    int c = 0;
    for (int t=0;t<T_SZ;++t) c += (tgt_vecs[tid*T_SZ + t] != 0) ? 1 : 0;
    s[tid] = loss_acc[tid] / (float)(c - 1);
  }
  __syncthreads();
  if (tid == 0){
    float a = 0.f;
    for (int b=0;b<16;++b) a += s[b];
    out[0] = a / 16.f;
  }
}

extern "C" void kernel_launch(void* const* d_in, const int* in_sizes, int n_in,
                              void* d_out, int out_size, void* d_ws, size_t ws_size,
                              hipStream_t stream){
  (void)in_sizes; (void)n_in; (void)out_size; (void)ws_size;
  const int*   src_vecs = (const int*)d_in[0];
  const float* src_mask = (const float*)d_in[1];
  const int*   tgt_vecs = (const int*)d_in[2];
  const float* enc_embed= (const float*)d_in[4];
  const float* dec_embed= (const float*)d_in[5];
  const float* eWih_f = (const float*)d_in[6];
  const float* eWhh_f = (const float*)d_in[7];
  const float* ebih_f = (const float*)d_in[8];
  const float* ebhh_f = (const float*)d_in[9];
  const float* eWih_b = (const float*)d_in[10];
  const float* eWhh_b = (const float*)d_in[11];
  const float* ebih_b = (const float*)d_in[12];
  const float* ebhh_b = (const float*)d_in[13];
  const float* dWih = (const float*)d_in[14];
  const float* dWhh = (const float*)d_in[15];
  const float* dbih = (const float*)d_in[16];
  const float* dbhh = (const float*)d_in[17];
  const float* aWh  = (const float*)d_in[18];
  const float* abh  = (const float*)d_in[19];
  const float* aWs  = (const float*)d_in[20];
  const float* abs_ = (const float*)d_in[21];
  const float* aWc  = (const float*)d_in[22];
  const float* abc  = (const float*)d_in[23];
  const float* aV   = (const float*)d_in[24];
  const float* abv  = (const float*)d_in[25];
  const float* rW   = (const float*)d_in[26];
  const float* rb   = (const float*)d_in[27];
  const float* gW   = (const float*)d_in[28];
  const float* gb   = (const float*)d_in[29];
  const float* fW   = (const float*)d_in[30];
  const float* fb   = (const float*)d_in[31];
  float* out = (float*)d_out;

  char* p = (char*)d_ws;
  auto alloc = [&](size_t n)->char*{ char* r = p; p += (n + 255) & ~(size_t)255; return r; };
  float* xs      = (float*)alloc((size_t)S_SZ*B_SZ*E_SZ*4);
  float* gi_f    = (float*)alloc((size_t)S_SZ*B_SZ*1536*4);
  float* gi_b    = (float*)alloc((size_t)S_SZ*B_SZ*1536*4);
  float* enc_out = (float*)alloc((size_t)B_SZ*S_SZ*1024*4);
  float* WhEnc   = (float*)alloc((size_t)B_SZ*S_SZ*512*4);
  float* dec_x   = (float*)alloc((size_t)(T_SZ-1)*B_SZ*E_SZ*4);
  float* dec_gi  = (float*)alloc((size_t)(T_SZ-1)*B_SZ*1536*4);
  float* gx      = (float*)alloc((size_t)(T_SZ-1)*B_SZ*4);
  float* eWihT_f = (float*)alloc((size_t)256*1536*4);
  float* eWihT_b = (float*)alloc((size_t)256*1536*4);
  float* dWihT   = (float*)alloc((size_t)256*1536*4);
  float* aWhT    = (float*)alloc((size_t)1024*512*4);
  float* aWsT    = (float*)alloc((size_t)512*512*4);
  float* rWT     = (float*)alloc((size_t)1024*512*4);
  u16* Wbf_f     = (u16*)alloc((size_t)1536*512*2);
  u16* Wbf_b     = (u16*)alloc((size_t)1536*512*2);
  u16* dWhhT     = (u16*)alloc((size_t)512*1536*2);
  u16* fwB       = (u16*)alloc((size_t)3125*16384*2);
  u16* h_bf      = (u16*)alloc((size_t)2*2*16*512*2);
  u16* u_bf      = (u16*)alloc((size_t)16*1024*2);
  int* bar       = (int*)alloc(64*4);
  float* enc_hid = (float*)alloc((size_t)B_SZ*1024*4);
  float* h_cur   = (float*)alloc((size_t)B_SZ*H_SZ*4);
  float* hdec    = (float*)alloc((size_t)B_SZ*H_SZ*4);
  float* s_part  = (float*)alloc((size_t)B_SZ*H_SZ*4);
  float* e_buf   = (float*)alloc((size_t)B_SZ*S_SZ*4);
  float* attn    = (float*)alloc((size_t)B_SZ*S_SZ*4);
  float* cov     = (float*)alloc((size_t)B_SZ*S_SZ*4);
  float* ctx     = (float*)alloc((size_t)B_SZ*1024*4);
  float* se_part = (float*)alloc((size_t)782*16*4);
  float* logit_tgt = (float*)alloc(64*4);
  float* covloss = (float*)alloc(64*4);
  float* loss_acc= (float*)alloc(64*4);

  dim3 tb(32,8);
  k_init<<<128,256,0,stream>>>((u32*)h_bf, bar, cov, loss_acc);
  k_transpose<<<dim3(8,48),tb,0,stream>>>(eWih_f, eWihT_f, 1536, 256);
  k_transpose<<<dim3(8,48),tb,0,stream>>>(eWih_b, eWihT_b, 1536, 256);
  k_transpose<<<dim3(8,48),tb,0,stream>>>(dWih, dWihT, 1536, 256);
  k_transpose<<<dim3(32,16),tb,0,stream>>>(aWh, aWhT, 512, 1024);
  k_transpose<<<dim3(16,16),tb,0,stream>>>(aWs, aWsT, 512, 512);
  k_transpose<<<dim3(32,16),tb,0,stream>>>(rW, rWT, 512, 1024);
  k_f2bf<<<3072,256,0,stream>>>(eWhh_f, Wbf_f, 1536*512);
  k_f2bf<<<3072,256,0,stream>>>(eWhh_b, Wbf_b, 1536*512);
  k_transpose_bf<<<dim3(16,48),tb,0,stream>>>(dWhh, dWhhT, 1536, 512);
  k_prep_fwB<<<25000,256,0,stream>>>(fW, fwB);
  k_gather_src<<<1024,256,0,stream>>>(src_vecs, enc_embed, xs);
  k_gather_dec<<<512,256,0,stream>>>(tgt_vecs, dec_embed, dec_x);
  k_gxscore<<<7,256,0,stream>>>(dec_x, gW, gx);
  k_gemm<<<dim3(24,200),256,0,stream>>>(xs, eWihT_f, ebih_f, gi_f, 6400,1536,256);
  k_gemm<<<dim3(24,200),256,0,stream>>>(xs, eWihT_b, ebih_b, gi_b, 6400,1536,256);
  k_gemm<<<dim3(24,50),256,0,stream>>>(dec_x, dWihT, dbih, dec_gi, 1584,1536,256);

  k_enc_persist<<<64,64,0,stream>>>(gi_f, gi_b, Wbf_f, Wbf_b, ebhh_f, ebhh_b,
                                    enc_out, enc_hid, h_bf, bar);

  k_gemm<<<dim3(8,1),256,0,stream>>>(enc_hid, rWT, rb, h_cur, 16,512,1024);
  k_gemm<<<dim3(8,200),256,0,stream>>>(enc_out, aWhT, abh, WhEnc, 6400,512,1024);

  for (int t=0;t<T_SZ-1;++t){
    k_dec_gru<<<64,384,0,stream>>>(dec_gi, h_cur, dWhhT, dbhh, hdec, u_bf, t);
    k_gemm<<<dim3(8,1),256,0,stream>>>(hdec, aWsT, abs_, s_part, 16,512,512);
    k_escore<<<128,512,0,stream>>>(WhEnc, s_part, cov, aWc, abc, aV, abv, src_mask, e_buf);
    k_attn_soft<<<16,512,0,stream>>>(e_buf, attn, cov, covloss);
    k_ctx<<<128,128,0,stream>>>(attn, enc_out, ctx);
    k_ctxred<<<8,256,0,stream>>>(ctx, rWT, rb, h_cur, u_bf);
    k_logits_mfma<<<782,256,0,stream>>>(u_bf, fwB, fb, tgt_vecs, se_part, logit_tgt, t);
    k_final<<<1,256,0,stream>>>(attn, src_vecs, tgt_vecs, h_cur, hdec, gW, gb, gx,
                                logit_tgt, se_part, covloss, loss_acc, t);
  }
  k_out<<<1,64,0,stream>>>(loss_acc, tgt_vecs, out);
}

// Round 3
// 18922.644 us; speedup vs baseline: 2.2280x; 1.3382x over previous
//
#include <hip/hip_runtime.h>

#define V_SZ 50000
#define E_SZ 256
#define H_SZ 512
#define B_SZ 16
#define S_SZ 400
#define T_SZ 100
#define UNK_TOK 1
#define NEGV -1e30f

typedef unsigned short u16;
typedef unsigned int u32;
typedef __attribute__((ext_vector_type(8))) short sv8;
typedef __attribute__((ext_vector_type(4))) float f32x4;

__device__ __forceinline__ float bf2f(u16 u){ return __uint_as_float(((u32)u)<<16); }
__device__ __forceinline__ u16 f2bf(float x){
  u32 u = __float_as_uint(x);
  u32 r = (u + 0x7fffu + ((u>>16)&1u)) >> 16;
  return (u16)r;
}
__device__ __forceinline__ float wsum(float v){
  #pragma unroll
  for (int o=32;o;o>>=1) v += __shfl_xor(v,o);
  return v;
}
__device__ __forceinline__ float wmaxf(float v){
  #pragma unroll
  for (int o=32;o;o>>=1) v = fmaxf(v, __shfl_xor(v,o));
  return v;
}
__device__ __forceinline__ float ftanh(float x){
  float y = fminf(18.f, fmaxf(-18.f, 2.f*x));
  float e = __expf(y);
  return (e-1.f)/(e+1.f);
}
__device__ __forceinline__ float sigf(float x){ return 1.f/(1.f+__expf(-x)); }

// ---------------- init ----------------
__global__ void k_init(u32* h_bf, int* flags, float* cov, float* loss_acc){
  int idx = blockIdx.x*256 + threadIdx.x;
  if (idx < 16384) h_bf[idx] = 0u;          // 2 bufs x 2 dirs x 16 b x 512 h bf16
  if (idx < 1024) flags[idx] = 0;           // 64 slots x 16 ints (64B stride)
  if (idx < B_SZ*S_SZ) cov[idx] = 0.f;
  if (idx < B_SZ) loss_acc[idx] = 0.f;
}

// ---------------- transposes / converts ----------------
__global__ void k_transpose(const float* __restrict__ in, float* __restrict__ out, int R, int C){
  __shared__ float t[32][33];
  int c0 = blockIdx.x*32, r0 = blockIdx.y*32;
  int x = threadIdx.x, y = threadIdx.y;
  for (int j=y;j<32;j+=8){
    int r=r0+j, c=c0+x;
    t[j][x] = (r<R && c<C) ? in[r*C+c] : 0.f;
  }
  __syncthreads();
  for (int j=y;j<32;j+=8){
    int oc = c0+j, orr = r0+x;
    if (oc<C && orr<R) out[oc*R+orr] = t[x][j];
  }
}
__global__ void k_f2bf(const float* __restrict__ in, u16* __restrict__ out, int n){
  for (int i = blockIdx.x*256 + threadIdx.x; i < n; i += gridDim.x*256) out[i] = f2bf(in[i]);
}
// W (Nt*16 rows x K cols) -> MFMA B-fragment-major bf16:
// out[((tile*K32+kk)*64+lane)*8 + j] = W[tile*16 + (lane&15)][kk*32 + (lane>>4)*8 + j]
__global__ void k_prep_frag(const float* __restrict__ W, u16* __restrict__ out, int Nt, int K32, int K){
  int idx = blockIdx.x*256 + threadIdx.x;
  if (idx >= Nt*K32*64) return;
  int lane = idx & 63; int kk = (idx>>6) % K32; int tile = idx / (K32*64);
  const float* src = W + (size_t)(tile*16 + (lane&15))*K + kk*32 + ((lane>>4)<<3);
  u16* dst = out + (size_t)idx*8;
  #pragma unroll
  for (int j=0;j<8;++j) dst[j] = f2bf(src[j]);
}

// ---------------- gathers ----------------
__global__ void k_gather_src(const int* __restrict__ src, const float* __restrict__ emb, float* __restrict__ xs){
  const int n = S_SZ*B_SZ*E_SZ;
  for (int idx = blockIdx.x*blockDim.x + threadIdx.x; idx < n; idx += gridDim.x*blockDim.x){
    int e = idx & 255; int sb = idx >> 8; int b = sb & 15; int s = sb >> 4;
    int tok = src[b*S_SZ + s]; if (tok >= V_SZ) tok = UNK_TOK;
    xs[idx] = emb[tok*E_SZ + e];
  }
}
__global__ void k_gather_dec(const int* __restrict__ tgt, const float* __restrict__ emb, float* __restrict__ dx){
  const int n = (T_SZ-1)*B_SZ*E_SZ;
  for (int idx = blockIdx.x*blockDim.x + threadIdx.x; idx < n; idx += gridDim.x*blockDim.x){
    int e = idx & 255; int tb = idx >> 8; int b = tb & 15; int t = tb >> 4;
    int tok = tgt[b*T_SZ + t]; if (tok >= V_SZ) tok = UNK_TOK;
    dx[idx] = emb[tok*E_SZ + e];
  }
}
__global__ void k_gxscore(const float* __restrict__ dx, const float* __restrict__ gW, float* __restrict__ gx){
  int i = blockIdx.x*blockDim.x + threadIdx.x;
  if (i < (T_SZ-1)*B_SZ){
    const float* x = dx + i*E_SZ;
    const float* g = gW + 1024;
    float a = 0.f;
    for (int e=0;e<E_SZ;++e) a += x[e]*g[e];
    gx[i] = a;
  }
}

// ---------------- generic GEMM: C(M,N) = A(M,K) @ WT(K,N) + bias(N) ----------------
__global__ __launch_bounds__(256) void k_gemm(const float* __restrict__ A, const float* __restrict__ WT,
                       const float* __restrict__ bias, float* __restrict__ C,
                       int M, int N, int K){
  __shared__ float As[32][36];
  int n = blockIdx.x*64 + (threadIdx.x & 63);
  int wv = threadIdx.x >> 6;
  int m0 = blockIdx.y*32;
  float acc[8];
  #pragma unroll
  for (int j=0;j<8;++j) acc[j]=0.f;
  for (int k0=0;k0<K;k0+=32){
    for (int e=threadIdx.x; e<1024; e+=256){
      int r = e>>5, c = e&31;
      int m = m0 + r;
      As[c][r] = (m<M)? A[m*K + k0 + c] : 0.f;
    }
    __syncthreads();
    #pragma unroll 8
    for (int k=0;k<32;++k){
      float w = WT[(k0+k)*N + n];
      const float* as = &As[k][wv*8];
      #pragma unroll
      for (int j=0;j<8;++j) acc[j] += as[j]*w;
    }
    __syncthreads();
  }
  float bv = bias[n];
  #pragma unroll
  for (int j=0;j<8;++j){
    int m = m0 + wv*8 + j;
    if (m<M) C[m*N + n] = acc[j] + bv;
  }
}

// ---------------- persistent bidirectional GRU encoder (flag-sync) ----------------
// 64 blocks x 64 threads (1 wave). block = dir*32 + slice (slice = 16 h-values).
// Flag slot per block (64B stride). Step t: wait all slots(dir) >= t, read h(t)
// from buf[t&1], write h(t+1) to buf[(t+1)&1], release-store flag=t+1.
// Safe: flag>=t from block B implies B finished READING h(t-1), so overwriting
// buf[(t+1)&1] (which held h(t-1)) is race-free with a single flag wave per step.
__global__ __launch_bounds__(64) void k_enc_persist(
    const float* __restrict__ gi_f, const float* __restrict__ gi_b,
    const u16* __restrict__ Wbf_f, const u16* __restrict__ Wbf_b,
    const float* __restrict__ bhh_f, const float* __restrict__ bhh_b,
    float* __restrict__ enc_out, float* __restrict__ enc_hid,
    u16* __restrict__ h_bf, int* __restrict__ flags){
  __shared__ u16 wl[48*512];   // 48KB
  int lane = threadIdx.x;
  int d = blockIdx.x >> 5, slice = blockIdx.x & 31;
  int h0 = slice*16;
  const u16* Wb = d ? Wbf_b : Wbf_f;
  const float* gi = d ? gi_b : gi_f;
  const float* bhh = d ? bhh_b : bhh_f;
  int hl = h0 + (lane & 15);
  int quad = lane >> 4;
  int* myflag = flags + (d*32 + slice)*16;
  int* pollp  = flags + (d*32 + (lane & 31))*16;

  // stage weight fragments: B[k][n] = Whh[gate*512 + h0 + n][k]
  #pragma unroll 4
  for (int i=0;i<48;++i){
    int gg = i>>4, kk = i&15;
    const u16* src = Wb + ((size_t)(gg*512 + hl))*512 + kk*32 + quad*8;
    *(sv8*)&wl[i*512 + lane*8] = *(const sv8*)src;
  }
  __syncthreads();

  float b0 = bhh[hl], b1 = bhh[512+hl], b2 = bhh[1024+hl];
  float hold[4] = {0.f,0.f,0.f,0.f};

  #pragma unroll 1
  for (int t=0;t<S_SZ;++t){
    int pos = d ? (S_SZ-1-t) : t;
    // gate-input loads (independent of h; issue before the wait)
    const float* gp = gi + ((size_t)pos*16)*1536 + hl;
    float giv[12];
    #pragma unroll
    for (int gg=0;gg<3;++gg)
      #pragma unroll
      for (int r=0;r<4;++r)
        giv[gg*4+r] = gp[(quad*4 + r)*1536 + gg*512];

    if (t > 0){
      while (true){
        int v = __hip_atomic_load(pollp, __ATOMIC_RELAXED, __HIP_MEMORY_SCOPE_AGENT);
        unsigned long long m = __ballot(v >= t);
        if (m == ~0ull) break;
        __builtin_amdgcn_s_sleep(1);
      }
      __threadfence();
    }

    const u16* hb = h_bf + ((size_t)(t&1)*2 + d)*8192 + (lane&15)*512 + quad*8;
    f32x4 a0={0.f,0.f,0.f,0.f}, a1={0.f,0.f,0.f,0.f}, a2={0.f,0.f,0.f,0.f};
    #pragma unroll
    for (int kk=0;kk<16;++kk){
      sv8 a = *(const sv8*)(hb + kk*32);
      a0 = __builtin_amdgcn_mfma_f32_16x16x32_bf16(a, *(const sv8*)&wl[(kk)*512 + lane*8], a0, 0,0,0);
      a1 = __builtin_amdgcn_mfma_f32_16x16x32_bf16(a, *(const sv8*)&wl[(16+kk)*512 + lane*8], a1, 0,0,0);
      a2 = __builtin_amdgcn_mfma_f32_16x16x32_bf16(a, *(const sv8*)&wl[(32+kk)*512 + lane*8], a2, 0,0,0);
    }
    u16* hw = h_bf + ((size_t)((t+1)&1)*2 + d)*8192;
    #pragma unroll
    for (int r=0;r<4;++r){
      int b = quad*4 + r;
      float rg = sigf(giv[r]   + a0[r] + b0);
      float zg = sigf(giv[4+r] + a1[r] + b1);
      float ng = ftanh(giv[8+r] + rg*(a2[r] + b2));
      float hv = (1.f-zg)*ng + zg*hold[r];
      hold[r] = hv;
      enc_out[((size_t)b*S_SZ + pos)*1024 + d*512 + hl] = hv;
      hw[b*512 + hl] = f2bf(hv);
      if (t == S_SZ-1) enc_hid[b*1024 + d*512 + hl] = hv;
    }
    __threadfence();
    if (lane == 0)
      __hip_atomic_store(myflag, t+1, __ATOMIC_RELEASE, __HIP_MEMORY_SCOPE_AGENT);
  }
}

// ---------------- decoder GRU via MFMA (carry = prev ctx_red, per reference) ----------------
// 32 blocks x 1 wave; block owns 16 h. A = ctx_red bf16 (u_bf lower half),
// B = prepped dWhh fragments. Writes hdec f32 + u_bf upper half bf16.
__global__ __launch_bounds__(64) void k_dec_mfma(
    const float* __restrict__ dec_gi, u16* __restrict__ u_bf,
    const u16* __restrict__ dfrag, const float* __restrict__ bhh,
    float* __restrict__ hdec, int t){
  int slice = blockIdx.x; int lane = threadIdx.x; int quad = lane >> 4;
  int h = slice*16 + (lane & 15);
  const u16* ap = u_bf + (lane&15)*1024 + quad*8;
  f32x4 a0={0.f,0.f,0.f,0.f}, a1=a0, a2=a0;
  #pragma unroll
  for (int kk=0;kk<16;++kk){
    sv8 a = *(const sv8*)(ap + kk*32);
    a0 = __builtin_amdgcn_mfma_f32_16x16x32_bf16(a, *(const sv8*)(dfrag + ((size_t)(0*32+slice)*16 + kk)*512 + lane*8), a0, 0,0,0);
    a1 = __builtin_amdgcn_mfma_f32_16x16x32_bf16(a, *(const sv8*)(dfrag + ((size_t)(1*32+slice)*16 + kk)*512 + lane*8), a1, 0,0,0);
    a2 = __builtin_amdgcn_mfma_f32_16x16x32_bf16(a, *(const sv8*)(dfrag + ((size_t)(2*32+slice)*16 + kk)*512 + lane*8), a2, 0,0,0);
  }
  float b0 = bhh[h], b1 = bhh[512+h], b2 = bhh[1024+h];
  const float* gi = dec_gi + (size_t)t*16*1536 + h;
  #pragma unroll
  for (int r=0;r<4;++r){
    int b = quad*4 + r;
    const float* gb_ = gi + b*1536;
    float hlv = bf2f(u_bf[b*1024 + h]);
    float rg = sigf(gb_[0]    + a0[r] + b0);
    float zg = sigf(gb_[512]  + a1[r] + b1);
    float ng = ftanh(gb_[1024] + rg*(a2[r] + b2));
    float hv = (1.f-zg)*ng + zg*hlv;
    hdec[b*512 + h] = hv;
    u_bf[b*1024 + 512 + h] = f2bf(hv);
  }
}

// ---------------- s_part = hdec @ aWs.T + abs_ via MFMA ----------------
__global__ __launch_bounds__(64) void k_spart_mfma(
    const u16* __restrict__ u_bf, const u16* __restrict__ sfrag,
    const float* __restrict__ abs_, float* __restrict__ s_part){
  int slice = blockIdx.x; int lane = threadIdx.x; int quad = lane >> 4;
  const u16* ap = u_bf + (lane&15)*1024 + 512 + quad*8;
  const u16* bp = sfrag + (size_t)slice*16*512 + lane*8;
  f32x4 acc={0.f,0.f,0.f,0.f};
  #pragma unroll
  for (int kk=0;kk<16;++kk){
    sv8 a = *(const sv8*)(ap + kk*32);
    acc = __builtin_amdgcn_mfma_f32_16x16x32_bf16(a, *(const sv8*)(bp + kk*512), acc, 0,0,0);
  }
  int h = slice*16 + (lane & 15);
  float bv = abs_[h];
  #pragma unroll
  for (int r=0;r<4;++r) s_part[(quad*4+r)*512 + h] = acc[r] + bv;
}

// ---------------- attention scores ----------------
__global__ __launch_bounds__(512) void k_escore(
    const float* __restrict__ WhEnc, const float* __restrict__ s_part,
    const float* __restrict__ cov, const float* __restrict__ aWc,
    const float* __restrict__ abc, const float* __restrict__ aV,
    const float* __restrict__ abv, const float* __restrict__ mask,
    float* __restrict__ e_buf){
  int b = blockIdx.x >> 3; int s0 = (blockIdx.x & 7)*50;
  int tid = threadIdx.x, lane = tid & 63, w = tid >> 6;
  __shared__ float sp[512], wc[512], ab[512], av[512];
  sp[tid] = s_part[b*H_SZ + tid];
  wc[tid] = aWc[tid];
  ab[tid] = abc[tid];
  av[tid] = aV[tid];
  __syncthreads();
  float abv0 = abv[0];
  for (int s = s0 + w; s < s0+50; s += 8){
    float cv = cov[b*S_SZ + s];
    const float* wh = WhEnc + (b*S_SZ + s)*H_SZ;
    float a = 0.f;
    #pragma unroll
    for (int j=0;j<8;++j){
      int h = j*64 + lane;
      a += ftanh(wh[h] + sp[h] + cv*wc[h] + ab[h]) * av[h];
    }
    a = wsum(a);
    if (lane == 0){
      float e = a + abv0;
      if (!(mask[b*S_SZ + s] > 0.f)) e = NEGV;
      e_buf[b*S_SZ + s] = e;
    }
  }
}

// ---------------- softmax + coverage update ----------------
__global__ __launch_bounds__(512) void k_attn_soft(
    const float* __restrict__ e_buf, float* __restrict__ attn,
    float* __restrict__ cov, float* __restrict__ covloss){
  int b = blockIdx.x; int tid = threadIdx.x, lane = tid & 63, w = tid >> 6;
  __shared__ float red[16];
  float e = (tid < S_SZ) ? e_buf[b*S_SZ + tid] : NEGV;
  float m = wmaxf(e);
  if (lane==0) red[w] = m;
  __syncthreads();
  if (tid < 64){
    float x = (lane < 8) ? red[lane] : NEGV;
    x = wmaxf(x);
    if (lane==0) red[8] = x;
  }
  __syncthreads();
  float mx = red[8];
  float pv = (tid < S_SZ) ? __expf(e - mx) : 0.f;
  float sm = wsum(pv);
  if (lane==0) red[w] = sm;
  __syncthreads();
  if (tid < 64){
    float x = (lane<8)? red[lane] : 0.f;
    x = wsum(x);
    if (lane==0) red[9] = x;
  }
  __syncthreads();
  float inv = 1.f/red[9];
  float ml = 0.f;
  if (tid < S_SZ){
    float a = pv*inv;
    attn[b*S_SZ+tid] = a;
    float cn = cov[b*S_SZ+tid] + a;
    cov[b*S_SZ+tid] = cn;
    ml = fminf(a, cn);
  }
  __syncthreads();
  float cs = wsum(ml);
  if (lane==0) red[w] = cs;
  __syncthreads();
  if (tid==0){
    float tot=0.f;
    for (int i=0;i<8;++i) tot += red[i];
    covloss[b] = tot;
  }
}

// ---------------- context vector ----------------
__global__ __launch_bounds__(128) void k_ctx(
    const float* __restrict__ attn, const float* __restrict__ enc_out,
    float* __restrict__ ctx){
  int b = blockIdx.x >> 3; int d0 = (blockIdx.x & 7)*128;
  int tid = threadIdx.x;
  float a = 0.f;
  const float* ao = attn + b*S_SZ;
  const float* eo = enc_out + b*S_SZ*1024 + d0 + tid;
  for (int s=0;s<S_SZ;++s) a += ao[s]*eo[s*1024];
  ctx[b*1024 + d0 + tid] = a;
}

// ---------------- ctx_red = ctx @ rW.T + rb ; writes h_cur (f32) + u_bf lower half ----------------
__global__ __launch_bounds__(256) void k_ctxred(const float* __restrict__ ctx, const float* __restrict__ rWT,
    const float* __restrict__ rb, float* __restrict__ h_cur, u16* __restrict__ u_bf){
  __shared__ float As[64][17];
  int lane = threadIdx.x & 63, wv = threadIdx.x >> 6;
  int n = blockIdx.x*64 + lane;
  float acc[4] = {0.f,0.f,0.f,0.f};
  for (int k0=0;k0<1024;k0+=64){
    for (int e=threadIdx.x; e<1024; e+=256){
      int r = e & 15, c = e >> 4;
      As[c][r] = ctx[r*1024 + k0 + c];
    }
    __syncthreads();
    #pragma unroll 8
    for (int k=0;k<64;++k){
      float w = rWT[(k0+k)*512 + n];
      #pragma unroll
      for (int j=0;j<4;++j) acc[j] += As[k][wv*4+j]*w;
    }
    __syncthreads();
  }
  float bv = rb[n];
  #pragma unroll
  for (int j=0;j<4;++j){
    int m = wv*4+j;
    float val = acc[j] + bv;
    h_cur[m*512 + n] = val;
    u_bf[m*1024 + n] = f2bf(val);
  }
}

// ---------------- vocab logits via MFMA ----------------
__global__ __launch_bounds__(256) void k_logits_mfma(
    const u16* __restrict__ u_bf, const u16* __restrict__ fwB,
    const float* __restrict__ fb, const int* __restrict__ tgt,
    float* __restrict__ se_part, float* __restrict__ logit_tgt, int t){
  int tid = threadIdx.x, lane = tid & 63, wv = tid >> 6;
  int tile = blockIdx.x*4 + wv;
  bool valid = tile < 3125;
  f32x4 acc = {0.f,0.f,0.f,0.f};
  if (valid){
    const u16* bp = fwB + (size_t)tile*16384 + lane*8;
    const u16* ap = u_bf + (lane&15)*1024 + (lane>>4)*8;
    #pragma unroll 8
    for (int kk=0;kk<32;++kk){
      sv8 a = *(const sv8*)(ap + kk*32);
      sv8 bfr = *(const sv8*)(bp + kk*512);
      acc = __builtin_amdgcn_mfma_f32_16x16x32_bf16(a, bfr, acc, 0,0,0);
    }
  }
  int v = tile*16 + (lane&15);
  float fbv = valid ? fb[v] : 0.f;
  float es0[4];
  #pragma unroll
  for (int r=0;r<4;++r){
    int b = (lane>>4)*4 + r;
    float lg = acc[r] + fbv;
    if (valid && v == tgt[b*T_SZ + t + 1]) logit_tgt[b] = lg;
    es0[r] = valid ? __expf(lg) : 0.f;
  }
  #pragma unroll
  for (int o=1;o<16;o<<=1){
    #pragma unroll
    for (int r=0;r<4;++r) es0[r] += __shfl_xor(es0[r], o);
  }
  __shared__ float part[4][16];
  if ((lane&15)==0){
    #pragma unroll
    for (int r=0;r<4;++r) part[wv][(lane>>4)*4+r] = es0[r];
  }
  __syncthreads();
  if (tid<16) se_part[blockIdx.x*16+tid] = part[0][tid]+part[1][tid]+part[2][tid]+part[3][tid];
}

// ---------------- per-step loss (+ p_gen folded in) ----------------
__global__ __launch_bounds__(256) void k_final(
    const float* __restrict__ attn, const int* __restrict__ src_vecs,
    const int* __restrict__ tgt_vecs, const float* __restrict__ h_cur,
    const float* __restrict__ hdec, const float* __restrict__ gW,
    const float* __restrict__ gb, const float* __restrict__ gx,
    const float* __restrict__ logit_tgt, const float* __restrict__ se_part,
    const float* __restrict__ covloss, float* __restrict__ loss_acc, int t){
  int tid = threadIdx.x, lane = tid&63, w = tid>>6;
  __shared__ float sume[16], pgen[16];
  for (int b = w; b < 16; b += 4){
    float a = 0.f;
    for (int i = lane; i < 782; i += 64) a += se_part[i*16 + b];
    a = wsum(a);
    float dd = 0.f;
    #pragma unroll
    for (int j=0;j<8;++j){
      int k = j*64 + lane;
      dd += h_cur[b*512+k]*gW[k] + hdec[b*512+k]*gW[512+k];
    }
    dd = wsum(dd);
    if (lane==0){
      sume[b] = a;
      float sc = dd + gx[t*B_SZ + b] + gb[0];
      float pg = sigf(sc);
      pgen[b] = fminf(0.999f, fmaxf(0.001f, pg));
    }
  }
  __syncthreads();
  for (int b = w; b < 16; b += 4){
    int tgt = tgt_vecs[b*T_SZ + t + 1];
    float sc = 0.f;
    for (int s = lane; s < S_SZ; s += 64){
      if (src_vecs[b*S_SZ + s] == tgt) sc += attn[b*S_SZ + s];
    }
    sc = wsum(sc);
    if (lane==0){
      float pg = pgen[b];
      float pvv = __expf(logit_tgt[b]) / sume[b];
      float tp = pg*pvv + (1.f-pg)*sc;
      float ls = -logf(tp + 1e-9f) + covloss[b];   // LAMB = 1
      if (tgt != 0) loss_acc[b] += ls;
    }
  }
}

// ---------------- output ----------------
__global__ void k_out(const float* __restrict__ loss_acc, const int* __restrict__ tgt_vecs, float* __restrict__ out){
  __shared__ float s[16];
  int tid = threadIdx.x;
  if (tid < 16){
    int c = 0;
    for (int t=0;t<T_SZ;++t) c += (tgt_vecs[tid*T_SZ + t] != 0) ? 1 : 0;
    s[tid] = loss_acc[tid] / (float)(c - 1);
  }
  __syncthreads();
  if (tid == 0){
    float a = 0.f;
    for (int b=0;b<16;++b) a += s[b];
    out[0] = a / 16.f;
  }
}

extern "C" void kernel_launch(void* const* d_in, const int* in_sizes, int n_in,
                              void* d_out, int out_size, void* d_ws, size_t ws_size,
                              hipStream_t stream){
  (void)in_sizes; (void)n_in; (void)out_size; (void)ws_size;
  const int*   src_vecs = (const int*)d_in[0];
  const float* src_mask = (const float*)d_in[1];
  const int*   tgt_vecs = (const int*)d_in[2];
  const float* enc_embed= (const float*)d_in[4];
  const float* dec_embed= (const float*)d_in[5];
  const float* eWih_f = (const float*)d_in[6];
  const float* eWhh_f = (const float*)d_in[7];
  const float* ebih_f = (const float*)d_in[8];
  const float* ebhh_f = (const float*)d_in[9];
  const float* eWih_b = (const float*)d_in[10];
  const float* eWhh_b = (const float*)d_in[11];
  const float* ebih_b = (const float*)d_in[12];
  const float* ebhh_b = (const float*)d_in[13];
  const float* dWih = (const float*)d_in[14];
  const float* dWhh = (const float*)d_in[15];
  const float* dbih = (const float*)d_in[16];
  const float* dbhh = (const float*)d_in[17];
  const float* aWh  = (const float*)d_in[18];
  const float* abh  = (const float*)d_in[19];
  const float* aWs  = (const float*)d_in[20];
  const float* abs_ = (const float*)d_in[21];
  const float* aWc  = (const float*)d_in[22];
  const float* abc  = (const float*)d_in[23];
  const float* aV   = (const float*)d_in[24];
  const float* abv  = (const float*)d_in[25];
  const float* rW   = (const float*)d_in[26];
  const float* rb   = (const float*)d_in[27];
  const float* gW   = (const float*)d_in[28];
  const float* gb   = (const float*)d_in[29];
  const float* fW   = (const float*)d_in[30];
  const float* fb   = (const float*)d_in[31];
  float* out = (float*)d_out;

  char* p = (char*)d_ws;
  auto alloc = [&](size_t n)->char*{ char* r = p; p += (n + 255) & ~(size_t)255; return r; };
  float* xs      = (float*)alloc((size_t)S_SZ*B_SZ*E_SZ*4);
  float* gi_f    = (float*)alloc((size_t)S_SZ*B_SZ*1536*4);
  float* gi_b    = (float*)alloc((size_t)S_SZ*B_SZ*1536*4);
  float* enc_out = (float*)alloc((size_t)B_SZ*S_SZ*1024*4);
  float* WhEnc   = (float*)alloc((size_t)B_SZ*S_SZ*512*4);
  float* dec_x   = (float*)alloc((size_t)(T_SZ-1)*B_SZ*E_SZ*4);
  float* dec_gi  = (float*)alloc((size_t)(T_SZ-1)*B_SZ*1536*4);
  float* gx      = (float*)alloc((size_t)(T_SZ-1)*B_SZ*4);
  float* eWihT_f = (float*)alloc((size_t)256*1536*4);
  float* eWihT_b = (float*)alloc((size_t)256*1536*4);
  float* dWihT   = (float*)alloc((size_t)256*1536*4);
  float* aWhT    = (float*)alloc((size_t)1024*512*4);
  float* rWT     = (float*)alloc((size_t)1024*512*4);
  u16* Wbf_f     = (u16*)alloc((size_t)1536*512*2);
  u16* Wbf_b     = (u16*)alloc((size_t)1536*512*2);
  u16* dfrag     = (u16*)alloc((size_t)96*16*512*2);
  u16* sfrag     = (u16*)alloc((size_t)32*16*512*2);
  u16* fwB       = (u16*)alloc((size_t)3125*16384*2);
  u16* h_bf      = (u16*)alloc((size_t)2*2*16*512*2);
  u16* u_bf      = (u16*)alloc((size_t)16*1024*2);
  int* flags     = (int*)alloc(64*16*4);
  float* enc_hid = (float*)alloc((size_t)B_SZ*1024*4);
  float* h_cur   = (float*)alloc((size_t)B_SZ*H_SZ*4);
  float* hdec    = (float*)alloc((size_t)B_SZ*H_SZ*4);
  float* s_part  = (float*)alloc((size_t)B_SZ*H_SZ*4);
  float* e_buf   = (float*)alloc((size_t)B_SZ*S_SZ*4);
  float* attn    = (float*)alloc((size_t)B_SZ*S_SZ*4);
  float* cov     = (float*)alloc((size_t)B_SZ*S_SZ*4);
  float* ctx     = (float*)alloc((size_t)B_SZ*1024*4);
  float* se_part = (float*)alloc((size_t)782*16*4);
  float* logit_tgt = (float*)alloc(64*4);
  float* covloss = (float*)alloc(64*4);
  float* loss_acc= (float*)alloc(64*4);

  dim3 tb(32,8);
  k_init<<<128,256,0,stream>>>((u32*)h_bf, flags, cov, loss_acc);
  k_transpose<<<dim3(8,48),tb,0,stream>>>(eWih_f, eWihT_f, 1536, 256);
  k_transpose<<<dim3(8,48),tb,0,stream>>>(eWih_b, eWihT_b, 1536, 256);
  k_transpose<<<dim3(8,48),tb,0,stream>>>(dWih, dWihT, 1536, 256);
  k_transpose<<<dim3(32,16),tb,0,stream>>>(aWh, aWhT, 512, 1024);
  k_transpose<<<dim3(32,16),tb,0,stream>>>(rW, rWT, 512, 1024);
  k_f2bf<<<3072,256,0,stream>>>(eWhh_f, Wbf_f, 1536*512);
  k_f2bf<<<3072,256,0,stream>>>(eWhh_b, Wbf_b, 1536*512);
  k_prep_frag<<<384,256,0,stream>>>(dWhh, dfrag, 96, 16, 512);
  k_prep_frag<<<128,256,0,stream>>>(aWs, sfrag, 32, 16, 512);
  k_prep_frag<<<25000,256,0,stream>>>(fW, fwB, 3125, 32, 1024);
  k_gather_src<<<1024,256,0,stream>>>(src_vecs, enc_embed, xs);
  k_gather_dec<<<512,256,0,stream>>>(tgt_vecs, dec_embed, dec_x);
  k_gxscore<<<7,256,0,stream>>>(dec_x, gW, gx);
  k_gemm<<<dim3(24,200),256,0,stream>>>(xs, eWihT_f, ebih_f, gi_f, 6400,1536,256);
  k_gemm<<<dim3(24,200),256,0,stream>>>(xs, eWihT_b, ebih_b, gi_b, 6400,1536,256);
  k_gemm<<<dim3(24,50),256,0,stream>>>(dec_x, dWihT, dbih, dec_gi, 1584,1536,256);

  k_enc_persist<<<64,64,0,stream>>>(gi_f, gi_b, Wbf_f, Wbf_b, ebhh_f, ebhh_b,
                                    enc_out, enc_hid, h_bf, flags);

  // h_dec0 = enc_hid @ rW.T + rb  (also seeds u_bf lower half for step 0)
  k_ctxred<<<8,256,0,stream>>>(enc_hid, rWT, rb, h_cur, u_bf);
  k_gemm<<<dim3(8,200),256,0,stream>>>(enc_out, aWhT, abh, WhEnc, 6400,512,1024);

  for (int t=0;t<T_SZ-1;++t){
    k_dec_mfma<<<32,64,0,stream>>>(dec_gi, u_bf, dfrag, dbhh, hdec, t);
    k_spart_mfma<<<32,64,0,stream>>>(u_bf, sfrag, abs_, s_part);
    k_escore<<<128,512,0,stream>>>(WhEnc, s_part, cov, aWc, abc, aV, abv, src_mask, e_buf);
    k_attn_soft<<<16,512,0,stream>>>(e_buf, attn, cov, covloss);
    k_ctx<<<128,128,0,stream>>>(attn, enc_out, ctx);
    k_ctxred<<<8,256,0,stream>>>(ctx, rWT, rb, h_cur, u_bf);
    k_logits_mfma<<<782,256,0,stream>>>(u_bf, fwB, fb, tgt_vecs, se_part, logit_tgt, t);
    k_final<<<1,256,0,stream>>>(attn, src_vecs, tgt_vecs, h_cur, hdec, gW, gb, gx,
                                logit_tgt, se_part, covloss, loss_acc, t);
  }
  k_out<<<1,64,0,stream>>>(loss_acc, tgt_vecs, out);
}